// Round 8
// baseline (150.272 us; speedup 1.0000x reference)
//
#include <hip/hip_runtime.h>
#include <hip/hip_bf16.h>
#include <stdint.h>

#define B_DIM 8
#define C_DIM 512
#define N_DIM 3136
#define NP    3200   // N padded to 25*128
#define BK    32
#define NT    25     // NP/128
#define NTRI  (NT * (NT + 1) / 2)  // 325 lower-tri block tiles

typedef short bf16x8 __attribute__((ext_vector_type(8)));
typedef float f32x4  __attribute__((ext_vector_type(4)));
typedef float f32x16 __attribute__((ext_vector_type(16)));

__device__ __forceinline__ void gload16(const void* g, void* l) {
  __builtin_amdgcn_global_load_lds(
      (const __attribute__((address_space(1))) void*)g,
      (__attribute__((address_space(3))) void*)l, 16, 0, 0);
}

__device__ __forceinline__ float bf2f(ushort u) {
  union { uint32_t i; float f; } c;
  c.i = ((uint32_t)u) << 16;
  return c.f;
}

__device__ __forceinline__ ushort f2bf(float f) {
  __hip_bfloat16 h = __float2bfloat16(f);
  return *(ushort*)&h;
}

// x[b][c][n] f32 -> kt[b][n][c] bf16 (n padded to NP, pad rows zero).
__global__ __launch_bounds__(256) void k_transpose(const float* __restrict__ x,
                                                   ushort* __restrict__ kt) {
  __shared__ float tile[64][33];
  const int b  = blockIdx.z;
  const int n0 = blockIdx.x * 32;
  const int c0 = blockIdx.y * 64;
  const int tx = threadIdx.x;
  const int ty = threadIdx.y;
#pragma unroll
  for (int j = 0; j < 8; ++j) {
    int c = c0 + ty + 8 * j;
    int n = n0 + tx;
    float v = (n < N_DIM) ? x[((size_t)b * C_DIM + c) * N_DIM + n] : 0.0f;
    tile[ty + 8 * j][tx] = v;
  }
  __syncthreads();
  const int tid = ty * 32 + tx;
  const int r = tid >> 5;
  const int p = tid & 31;
#pragma unroll
  for (int i = 0; i < 4; ++i) {
    int nl = r + 8 * i;
    int n = n0 + nl;
    uint32_t u = (uint32_t)f2bf(tile[2 * p][nl]) |
                 ((uint32_t)f2bf(tile[2 * p + 1][nl]) << 16);
    *(uint32_t*)(kt + ((size_t)b * NP + n) * C_DIM + c0 + 2 * p) = u;
  }
}

// sq[b*NP+n] = sum_c kt[b][n][c]^2 (fp32 accum over bf16 values).
__global__ __launch_bounds__(256) void k_norms(const ushort* __restrict__ kt,
                                               float* __restrict__ sq) {
  const int row  = blockIdx.x * 4 + (threadIdx.x >> 6);
  const int lane = threadIdx.x & 63;
  const ushort* p = kt + (size_t)row * C_DIM + lane * 8;
  bf16x8 v = *(const bf16x8*)p;
  float s = 0.0f;
#pragma unroll
  for (int j = 0; j < 8; ++j) {
    float f = bf2f((ushort)v[j]);
    s += f * f;
  }
#pragma unroll
  for (int m = 32; m >= 1; m >>= 1) s += __shfl_xor(s, m);
  if (lane == 0) sq[row] = s;
}

// Symmetric GEMM, lower-tri tiles, R3 skeleton with 32x32x16 MFMA.
// Per wave: 64x64 sub-tile = 2x2 frags of 32x32 (acc f32x16 each).
// A/B frag per lane: row/col = lane&31, k = (lane>>5)*8 + j.
// C/D (m74/m101): col = lane&31, row = (reg&3) + 8*(reg>>2) + 4*(lane>>5).
__global__ __launch_bounds__(256) void k_gemm(const ushort* __restrict__ kt,
                                              const float* __restrict__ sq,
                                              float* __restrict__ out) {
  // union: staging tiles (16 KB) in main loop; [64][132] f32 (33.8 KB) mirror
  __shared__ __attribute__((aligned(16))) char smem[64 * 132 * 4];
  ushort* tA = (ushort*)smem;            // [128][32] bf16, 8 KB
  ushort* tB = (ushort*)(smem + 8192);   // [128][32] bf16, 8 KB
  float*  tr = (float*)smem;

  const int id = blockIdx.x;
  const int b = id & 7;
  const int t = id >> 3;
  int bx = (int)((sqrtf(8.0f * (float)t + 1.0f) - 1.0f) * 0.5f);
  while ((bx + 1) * (bx + 2) / 2 <= t) ++bx;
  while (bx * (bx + 1) / 2 > t) --bx;
  const int by = t - bx * (bx + 1) / 2;

  const int n0 = bx * 128;  // rows
  const int m0 = by * 128;  // cols
  const int tid  = threadIdx.x;
  const int wave = tid >> 6;
  const int lane = tid & 63;
  const ushort* ktb = kt + (size_t)b * NP * C_DIM;

  const int wr = (wave >> 1) * 64;
  const int wc = (wave & 1) * 64;
  const int lr = lane & 31;   // frag row/col
  const int kh = lane >> 5;   // k-half selector

  f32x16 acc[2][2];
#pragma unroll
  for (int fr = 0; fr < 2; ++fr)
#pragma unroll
    for (int fc = 0; fc < 2; ++fc)
#pragma unroll
      for (int r = 0; r < 16; ++r)
        acc[fr][fc][r] = 0.0f;

  for (int ks = 0; ks < C_DIM / BK; ++ks) {
    __syncthreads();
    const int kbase = ks * BK;
#pragma unroll
    for (int i = 0; i < 2; ++i) {
      int q   = i * 256 + wave * 64 + lane;   // 16B chunk index 0..511
      int row = q >> 2;
      int lk  = (q & 3) ^ ((q >> 3) & 3);     // pre-swizzled global source
      const ushort* gA = ktb + (size_t)(n0 + row) * C_DIM + kbase + lk * 8;
      const ushort* gB = ktb + (size_t)(m0 + row) * C_DIM + kbase + lk * 8;
      char* lA = (char*)tA + (i * 256 + wave * 64) * 16;  // wave-uniform base
      char* lB = (char*)tB + (i * 256 + wave * 64) * 16;
      gload16(gA, lA);
      gload16(gB, lB);
    }
    __syncthreads();

#pragma unroll
    for (int s = 0; s < 2; ++s) {
      bf16x8 aF[2], bF[2];
#pragma unroll
      for (int fr = 0; fr < 2; ++fr) {
        int row  = wr + fr * 32 + lr;
        int phys = (s * 2 + kh) ^ ((row >> 1) & 3);
        aF[fr] = *(const bf16x8*)((const char*)tA + row * 64 + phys * 16);
      }
#pragma unroll
      for (int fc = 0; fc < 2; ++fc) {
        int row  = wc + fc * 32 + lr;
        int phys = (s * 2 + kh) ^ ((row >> 1) & 3);
        bF[fc] = *(const bf16x8*)((const char*)tB + row * 64 + phys * 16);
      }
#pragma unroll
      for (int fr = 0; fr < 2; ++fr)
#pragma unroll
        for (int fc = 0; fc < 2; ++fc)
          acc[fr][fc] = __builtin_amdgcn_mfma_f32_32x32x16_bf16(
              aF[fr], bF[fc], acc[fr][fc], 0, 0, 0);
    }
  }

  // ---- epilogue: normalize ----
  const float* sqb = sq + b * NP;
  float rcol[2], rrow[2][4][4];
#pragma unroll
  for (int fc = 0; fc < 2; ++fc) {
    float s = sqb[m0 + wc + fc * 32 + lr];
    rcol[fc] = 1.0f / fmaxf(sqrtf(s), 1e-8f);
  }
#pragma unroll
  for (int fr = 0; fr < 2; ++fr)
#pragma unroll
    for (int g = 0; g < 4; ++g)
#pragma unroll
      for (int j = 0; j < 4; ++j) {
        float s = sqb[n0 + wr + fr * 32 + 8 * g + 4 * kh + j];
        rrow[fr][g][j] = 1.0f / fmaxf(sqrtf(s), 1e-8f);
      }
#pragma unroll
  for (int fr = 0; fr < 2; ++fr)
#pragma unroll
    for (int fc = 0; fc < 2; ++fc)
#pragma unroll
      for (int g = 0; g < 4; ++g)
#pragma unroll
        for (int j = 0; j < 4; ++j)
          acc[fr][fc][g * 4 + j] *= rrow[fr][g][j] * rcol[fc];

  float* outb = out + (size_t)b * N_DIM * N_DIM;

  // direct write: out[row][col]; per instr 2 rows x 32 consecutive cols = 2x128B
#pragma unroll
  for (int fr = 0; fr < 2; ++fr) {
#pragma unroll
    for (int fc = 0; fc < 2; ++fc) {
      int col = m0 + wc + fc * 32 + lr;
#pragma unroll
      for (int g = 0; g < 4; ++g)
#pragma unroll
        for (int j = 0; j < 4; ++j) {
          int row = n0 + wr + fr * 32 + 8 * g + 4 * kh + j;
          if (row < N_DIM && col < N_DIM)
            outb[(size_t)row * N_DIM + col] = acc[fr][fc][g * 4 + j];
        }
    }
  }

  // mirror write: out[col][row] via LDS transpose, two 64-col passes
  if (bx != by) {
#pragma unroll
    for (int h = 0; h < 2; ++h) {
      __syncthreads();
      if ((wave & 1) == h) {
#pragma unroll
        for (int fr = 0; fr < 2; ++fr)
#pragma unroll
          for (int fc = 0; fc < 2; ++fc) {
            int colL = fc * 32 + lr;  // 0..63 (this wave's cols)
#pragma unroll
            for (int g = 0; g < 4; ++g) {
              int rowL = wr + fr * 32 + 8 * g + 4 * kh;  // 16B-aligned
              f32x4 v = {acc[fr][fc][g * 4 + 0], acc[fr][fc][g * 4 + 1],
                         acc[fr][fc][g * 4 + 2], acc[fr][fc][g * 4 + 3]};
              *(f32x4*)(tr + colL * 132 + rowL) = v;
            }
          }
      }
      __syncthreads();
#pragma unroll
      for (int it = 0; it < 8; ++it) {
        int i  = it * 8 + (tid >> 5);   // local mirror row 0..63
        int j4 = (tid & 31) * 4;        // col chunk
        int gm = m0 + h * 64 + i;       // out row (= original col)
        int gn = n0 + j4;               // out col (= original row)
        if (gm < N_DIM && gn < N_DIM) {
          f32x4 v = *(const f32x4*)(tr + i * 132 + j4);
          *(f32x4*)(outb + (size_t)gm * N_DIM + gn) = v;
        }
      }
    }
  }
}

extern "C" void kernel_launch(void* const* d_in, const int* in_sizes, int n_in,
                              void* d_out, int out_size, void* d_ws, size_t ws_size,
                              hipStream_t stream) {
  const float* x = (const float*)d_in[0];
  float* out = (float*)d_out;

  ushort* kt = (ushort*)d_ws;
  float* sq = (float*)((char*)d_ws + (size_t)B_DIM * NP * C_DIM * 2);

  dim3 gT(NP / 32, C_DIM / 64, B_DIM);
  k_transpose<<<gT, dim3(32, 8), 0, stream>>>(x, kt);

  k_norms<<<B_DIM * NP / 4, 256, 0, stream>>>(kt, sq);

  k_gemm<<<NTRI * B_DIM, 256, 0, stream>>>(kt, sq, out);
}

// Round 9
// 126.572 us; speedup vs baseline: 1.1872x; 1.1872x over previous
//
#include <hip/hip_runtime.h>
#include <hip/hip_bf16.h>
#include <stdint.h>

#define B_DIM 8
#define C_DIM 512
#define N_DIM 3136
#define NP    3200   // N padded to 25*128
#define BK    32
#define NT    25     // NP/128
#define NTRI  (NT * (NT + 1) / 2)  // 325 lower-tri block tiles

typedef short bf16x8 __attribute__((ext_vector_type(8)));
typedef float f32x4  __attribute__((ext_vector_type(4)));

__device__ __forceinline__ void gload16(const void* g, void* l) {
  __builtin_amdgcn_global_load_lds(
      (const __attribute__((address_space(1))) void*)g,
      (__attribute__((address_space(3))) void*)l, 16, 0, 0);
}

__device__ __forceinline__ float bf2f(ushort u) {
  union { uint32_t i; float f; } c;
  c.i = ((uint32_t)u) << 16;
  return c.f;
}

__device__ __forceinline__ ushort f2bf(float f) {
  __hip_bfloat16 h = __float2bfloat16(f);
  return *(ushort*)&h;
}

// x[b][c][n] f32 -> kt[b][n][c] bf16 (n padded to NP, pad rows zero).
__global__ __launch_bounds__(256) void k_transpose(const float* __restrict__ x,
                                                   ushort* __restrict__ kt) {
  __shared__ float tile[64][33];
  const int b  = blockIdx.z;
  const int n0 = blockIdx.x * 32;
  const int c0 = blockIdx.y * 64;
  const int tx = threadIdx.x;
  const int ty = threadIdx.y;
#pragma unroll
  for (int j = 0; j < 8; ++j) {
    int c = c0 + ty + 8 * j;
    int n = n0 + tx;
    float v = (n < N_DIM) ? x[((size_t)b * C_DIM + c) * N_DIM + n] : 0.0f;
    tile[ty + 8 * j][tx] = v;
  }
  __syncthreads();
  const int tid = ty * 32 + tx;
  const int r = tid >> 5;
  const int p = tid & 31;
#pragma unroll
  for (int i = 0; i < 4; ++i) {
    int nl = r + 8 * i;
    int n = n0 + nl;
    uint32_t u = (uint32_t)f2bf(tile[2 * p][nl]) |
                 ((uint32_t)f2bf(tile[2 * p + 1][nl]) << 16);
    *(uint32_t*)(kt + ((size_t)b * NP + n) * C_DIM + c0 + 2 * p) = u;
  }
}

// sq[b*NP+n] = sum_c kt[b][n][c]^2 (fp32 accum over bf16 values).
__global__ __launch_bounds__(256) void k_norms(const ushort* __restrict__ kt,
                                               float* __restrict__ sq) {
  const int row  = blockIdx.x * 4 + (threadIdx.x >> 6);
  const int lane = threadIdx.x & 63;
  const ushort* p = kt + (size_t)row * C_DIM + lane * 8;
  bf16x8 v = *(const bf16x8*)p;
  float s = 0.0f;
#pragma unroll
  for (int j = 0; j < 8; ++j) {
    float f = bf2f((ushort)v[j]);
    s += f * f;
  }
#pragma unroll
  for (int m = 32; m >= 1; m >>= 1) s += __shfl_xor(s, m);
  if (lane == 0) sq[row] = s;
}

// Symmetric GEMM, lower-tri tiles. R3 structure verbatim; output stores are
// NON-TEMPORAL (nt) so the 315 MB write stream doesn't evict the batch-pinned
// kt panels from each XCD's 4MB L2 (staging reads stay L2-resident).
__global__ __launch_bounds__(256) void k_gemm(const ushort* __restrict__ kt,
                                              const float* __restrict__ sq,
                                              float* __restrict__ out) {
  __shared__ __attribute__((aligned(16))) char smem[64 * 132 * 4];
  ushort* tA = (ushort*)smem;            // [128][32] bf16, 8 KB
  ushort* tB = (ushort*)(smem + 8192);   // [128][32] bf16, 8 KB
  float*  tr = (float*)smem;             // [64][132] f32 (epilogue union)

  const int id = blockIdx.x;
  const int b = id & 7;        // batch -> XCD round-robin
  const int t = id >> 3;       // triangular tile index 0..324
  int bx = (int)((sqrtf(8.0f * (float)t + 1.0f) - 1.0f) * 0.5f);
  while ((bx + 1) * (bx + 2) / 2 <= t) ++bx;
  while (bx * (bx + 1) / 2 > t) --bx;
  const int by = t - bx * (bx + 1) / 2;

  const int n0 = bx * 128;  // rows (A tile)
  const int m0 = by * 128;  // cols (B tile)
  const int tid  = threadIdx.x;
  const int wave = tid >> 6;
  const int lane = tid & 63;
  const ushort* ktb = kt + (size_t)b * NP * C_DIM;

  const int wr = (wave >> 1) * 64;
  const int wc = (wave & 1) * 64;
  const int koff = lane >> 4;
  const int rl = lane & 15;

  f32x4 acc[4][4];
#pragma unroll
  for (int mi = 0; mi < 4; ++mi)
#pragma unroll
    for (int ni = 0; ni < 4; ++ni)
      acc[mi][ni] = (f32x4){0.f, 0.f, 0.f, 0.f};

  for (int ks = 0; ks < C_DIM / BK; ++ks) {
    __syncthreads();
    const int kbase = ks * BK;
#pragma unroll
    for (int i = 0; i < 2; ++i) {
      int q   = i * 256 + wave * 64 + lane;   // 16B chunk index 0..511
      int row = q >> 2;
      int lk  = (q & 3) ^ ((q >> 3) & 3);     // pre-swizzled global source
      const ushort* gA = ktb + (size_t)(n0 + row) * C_DIM + kbase + lk * 8;
      const ushort* gB = ktb + (size_t)(m0 + row) * C_DIM + kbase + lk * 8;
      char* lA = (char*)tA + (i * 256 + wave * 64) * 16;  // wave-uniform base
      char* lB = (char*)tB + (i * 256 + wave * 64) * 16;
      gload16(gA, lA);
      gload16(gB, lB);
    }
    __syncthreads();

    bf16x8 aF[4], bF[4];
#pragma unroll
    for (int mi = 0; mi < 4; ++mi) {
      int row  = wr + mi * 16 + rl;
      int phys = koff ^ ((row >> 1) & 3);
      aF[mi] = *(const bf16x8*)((const char*)tA + row * 64 + phys * 16);
    }
#pragma unroll
    for (int ni = 0; ni < 4; ++ni) {
      int row  = wc + ni * 16 + rl;
      int phys = koff ^ ((row >> 1) & 3);
      bF[ni] = *(const bf16x8*)((const char*)tB + row * 64 + phys * 16);
    }
#pragma unroll
    for (int mi = 0; mi < 4; ++mi)
#pragma unroll
      for (int ni = 0; ni < 4; ++ni)
        acc[mi][ni] = __builtin_amdgcn_mfma_f32_16x16x32_bf16(
            aF[mi], bF[ni], acc[mi][ni], 0, 0, 0);
  }

  // ---- epilogue: normalize ----
  const float* sqb = sq + b * NP;
  float rrow[4][4], rcol[4];
#pragma unroll
  for (int mi = 0; mi < 4; ++mi)
#pragma unroll
    for (int r = 0; r < 4; ++r) {
      float s = sqb[n0 + wr + mi * 16 + koff * 4 + r];
      rrow[mi][r] = 1.0f / fmaxf(sqrtf(s), 1e-8f);
    }
#pragma unroll
  for (int ni = 0; ni < 4; ++ni) {
    float s = sqb[m0 + wc + ni * 16 + rl];
    rcol[ni] = 1.0f / fmaxf(sqrtf(s), 1e-8f);
  }
#pragma unroll
  for (int mi = 0; mi < 4; ++mi)
#pragma unroll
    for (int ni = 0; ni < 4; ++ni)
#pragma unroll
      for (int r = 0; r < 4; ++r)
        acc[mi][ni][r] *= rrow[mi][r] * rcol[ni];

  float* outb = out + (size_t)b * N_DIM * N_DIM;

  // direct write: out[n0+row][m0+col] — coalesced, non-temporal
#pragma unroll
  for (int mi = 0; mi < 4; ++mi) {
#pragma unroll
    for (int ni = 0; ni < 4; ++ni) {
#pragma unroll
      for (int r = 0; r < 4; ++r) {
        int row = n0 + wr + mi * 16 + koff * 4 + r;
        int col = m0 + wc + ni * 16 + rl;
        if (row < N_DIM && col < N_DIM)
          __builtin_nontemporal_store(acc[mi][ni][r],
                                      outb + (size_t)row * N_DIM + col);
      }
    }
  }

  // mirror write via LDS transpose, two 64-col passes, non-temporal x4 stores
  if (bx != by) {
#pragma unroll
    for (int h = 0; h < 2; ++h) {
      __syncthreads();
      if ((wave & 1) == h) {
#pragma unroll
        for (int ni = 0; ni < 4; ++ni) {
          int colL = ni * 16 + rl;  // 0..63
#pragma unroll
          for (int mi = 0; mi < 4; ++mi) {
            int row = wr + mi * 16 + koff * 4;  // 16B-aligned
            *(f32x4*)(tr + colL * 132 + row) = acc[mi][ni];
          }
        }
      }
      __syncthreads();
#pragma unroll
      for (int it = 0; it < 8; ++it) {
        int i  = it * 8 + (tid >> 5);   // local mirror row 0..63
        int j4 = (tid & 31) * 4;        // col chunk
        int gm = m0 + h * 64 + i;       // global row (= original col)
        int gn = n0 + j4;               // global col (= original row)
        if (gm < N_DIM && gn < N_DIM) {
          f32x4 v = *(const f32x4*)(tr + i * 132 + j4);
          __builtin_nontemporal_store(
              v, (f32x4*)(outb + (size_t)gm * N_DIM + gn));
        }
      }
    }
  }
}

extern "C" void kernel_launch(void* const* d_in, const int* in_sizes, int n_in,
                              void* d_out, int out_size, void* d_ws, size_t ws_size,
                              hipStream_t stream) {
  const float* x = (const float*)d_in[0];
  float* out = (float*)d_out;

  ushort* kt = (ushort*)d_ws;
  float* sq = (float*)((char*)d_ws + (size_t)B_DIM * NP * C_DIM * 2);

  dim3 gT(NP / 32, C_DIM / 64, B_DIM);  // 100,8,8
  k_transpose<<<gT, dim3(32, 8), 0, stream>>>(x, kt);

  k_norms<<<B_DIM * NP / 4, 256, 0, stream>>>(kt, sq);

  k_gemm<<<NTRI * B_DIM, 256, 0, stream>>>(kt, sq, out);  // 2600 blocks
}